// Round 1
// baseline (517.040 us; speedup 1.0000x reference)
//
#include <hip/hip_runtime.h>
#include <math.h>

#define N_SIMP 8192
#define K_FILT 8
#define BATCH  64
#define FEAT   128
#define MCHUNK 64   // m-chunks for wL partials
#define NCHUNK 64   // n-chunks for conv partials

// ============================================================================
// FAST PATH (two-stage, no atomics) — needs ws >= 16 MB partials + 256 KB wL
// ============================================================================

// ---------------------------------------------------------------------------
// wl_partial: pL[mc][k][n] = sum_{m in chunk mc} W[k][m] * L[m][n]
// grid = 8 n-tiles (1024 cols) x 64 m-chunks (128 rows) = 512 blocks, 256 thr
// 8 rows/iter + 1-iter-ahead register prefetch: 8 float4 loads continuously in
// flight per wave (8 KB/wave) so the memory pipe never drains during FMAs.
// ---------------------------------------------------------------------------
__global__ __launch_bounds__(256) void wl_partial_kernel(const float* __restrict__ W,
                                                         const float* __restrict__ L,
                                                         float* __restrict__ pL) {
    const int ntile = blockIdx.x & 7;
    const int mc    = blockIdx.x >> 3;
    const int n0    = ntile * 1024;
    const int m0    = mc * 128;

    __shared__ float Ws[K_FILT][128];
    for (int idx = threadIdx.x; idx < K_FILT * 128; idx += 256) {
        int k = idx >> 7, j = idx & 127;
        Ws[k][j] = W[k * N_SIMP + m0 + j];
    }
    __syncthreads();

    const int n = n0 + threadIdx.x * 4;
    float4 acc[K_FILT];
#pragma unroll
    for (int k = 0; k < K_FILT; k++) acc[k] = make_float4(0.f, 0.f, 0.f, 0.f);

    const float* Lp = L + (size_t)m0 * N_SIMP + n;

    float4 c[8];
#pragma unroll
    for (int r = 0; r < 8; r++) c[r] = *(const float4*)(Lp + (size_t)r * N_SIMP);
    Lp += 8 * (size_t)N_SIMP;

    for (int j0 = 0; j0 < 120; j0 += 8) {
        // prefetch next 8 rows while computing current 8
        float4 nx[8];
#pragma unroll
        for (int r = 0; r < 8; r++) nx[r] = *(const float4*)(Lp + (size_t)r * N_SIMP);
        Lp += 8 * (size_t)N_SIMP;

#pragma unroll
        for (int k = 0; k < K_FILT; k++) {
#pragma unroll
            for (int r = 0; r < 8; r++) {
                float w = Ws[k][j0 + r];
                acc[k].x += w * c[r].x; acc[k].y += w * c[r].y;
                acc[k].z += w * c[r].z; acc[k].w += w * c[r].w;
            }
        }
#pragma unroll
        for (int r = 0; r < 8; r++) c[r] = nx[r];
    }
    // tail: rows 120..127 already in c[]
#pragma unroll
    for (int k = 0; k < K_FILT; k++) {
#pragma unroll
        for (int r = 0; r < 8; r++) {
            float w = Ws[k][120 + r];
            acc[k].x += w * c[r].x; acc[k].y += w * c[r].y;
            acc[k].z += w * c[r].z; acc[k].w += w * c[r].w;
        }
    }

#pragma unroll
    for (int k = 0; k < K_FILT; k++)
        *(float4*)&pL[(size_t)(mc * K_FILT + k) * N_SIMP + n] = acc[k];
}

// ---------------------------------------------------------------------------
// reduce64: out[i] = (TANH? tanh:id)(sum_{c=0..63} p[c*65536 + i]), i<65536.
// 256 blocks x 256 thr; each output float4 is split 4 ways across the
// chunk range (g = tid>>6 handles chunks g*16..g*16+15), LDS-combined.
// 4x the CU coverage and 4x shorter load chains vs the old 64-block version.
// Works for both pL (chunk stride K*N = 65536) and pO (K*B*F = 65536).
// ---------------------------------------------------------------------------
template <bool TANH>
__global__ __launch_bounds__(256) void reduce64_kernel(const float* __restrict__ p,
                                                       float* __restrict__ out) {
    const int t  = threadIdx.x & 63;
    const int g  = threadIdx.x >> 6;           // 0..3
    const int i4 = blockIdx.x * 256 + t * 4;

    const float* base = p + (size_t)(g * 16) * 65536 + i4;
    float4 s = make_float4(0.f, 0.f, 0.f, 0.f);
#pragma unroll
    for (int mc = 0; mc < 16; mc++) {
        float4 v = *(const float4*)(base + (size_t)mc * 65536);
        s.x += v.x; s.y += v.y; s.z += v.z; s.w += v.w;
    }

    __shared__ float4 red[4][64];
    red[g][t] = s;
    __syncthreads();

    if (g == 0) {
        float4 a = red[1][t], b = red[2][t], c = red[3][t];
        s.x += a.x + b.x + c.x;
        s.y += a.y + b.y + c.y;
        s.z += a.z + b.z + c.z;
        s.w += a.w + b.w + c.w;
        if (TANH) {
            s.x = tanhf(s.x); s.y = tanhf(s.y); s.z = tanhf(s.z); s.w = tanhf(s.w);
        }
        *(float4*)&out[i4] = s;
    }
}

// ---------------------------------------------------------------------------
// conv_partial: pO[nc][k][b][f] = sum_{n in chunk nc} wL[k][n] * x[b][n][f]
// grid = 64 b x 64 n-chunks (128 n) = 4096 blocks, 64 threads (1 wave).
// lanes 0-31: rows j even (f via float4); lanes 32-63: rows j odd.
// 8 rows/iter + 1-iter-ahead register prefetch (4 float4 loads sustained).
// ---------------------------------------------------------------------------
__global__ __launch_bounds__(64) void conv_partial_kernel(const float* __restrict__ wL,
                                                          const float* __restrict__ x,
                                                          float* __restrict__ pO) {
    const int nc   = blockIdx.x & 63;
    const int b    = blockIdx.x >> 6;
    const int n0   = nc * 128;
    const int lane = threadIdx.x;
    const int f0   = (lane & 31) * 4;
    const int nl   = lane >> 5;

    __shared__ float wls[K_FILT][128];
    for (int idx = lane; idx < K_FILT * 128; idx += 64) {
        int k = idx >> 7, j = idx & 127;
        wls[k][j] = wL[k * N_SIMP + n0 + j];
    }
    __syncthreads();

    float4 acc[K_FILT];
#pragma unroll
    for (int k = 0; k < K_FILT; k++) acc[k] = make_float4(0.f, 0.f, 0.f, 0.f);

    auto compute = [&](int j0, const float4& x0, const float4& x1,
                       const float4& x2, const float4& x3) {
#pragma unroll
        for (int k = 0; k < K_FILT; k++) {
            float w0 = wls[k][j0 + 0 + nl];
            float w1 = wls[k][j0 + 2 + nl];
            float w2 = wls[k][j0 + 4 + nl];
            float w3 = wls[k][j0 + 6 + nl];
            acc[k].x += w0 * x0.x; acc[k].y += w0 * x0.y; acc[k].z += w0 * x0.z; acc[k].w += w0 * x0.w;
            acc[k].x += w1 * x1.x; acc[k].y += w1 * x1.y; acc[k].z += w1 * x1.z; acc[k].w += w1 * x1.w;
            acc[k].x += w2 * x2.x; acc[k].y += w2 * x2.y; acc[k].z += w2 * x2.z; acc[k].w += w2 * x2.w;
            acc[k].x += w3 * x3.x; acc[k].y += w3 * x3.y; acc[k].z += w3 * x3.z; acc[k].w += w3 * x3.w;
        }
    };

    const float* xp = x + (size_t)b * N_SIMP * FEAT + (size_t)(n0 + nl) * FEAT + f0;
    float4 c0 = *(const float4*)(xp);
    float4 c1 = *(const float4*)(xp + 2 * FEAT);
    float4 c2 = *(const float4*)(xp + 4 * FEAT);
    float4 c3 = *(const float4*)(xp + 6 * FEAT);
    xp += 8 * FEAT;

    for (int j0 = 0; j0 < 120; j0 += 8) {
        float4 p0 = *(const float4*)(xp);
        float4 p1 = *(const float4*)(xp + 2 * FEAT);
        float4 p2 = *(const float4*)(xp + 4 * FEAT);
        float4 p3 = *(const float4*)(xp + 6 * FEAT);
        xp += 8 * FEAT;
        compute(j0, c0, c1, c2, c3);
        c0 = p0; c1 = p1; c2 = p2; c3 = p3;
    }
    compute(120, c0, c1, c2, c3);

#pragma unroll
    for (int k = 0; k < K_FILT; k++) {
        acc[k].x += __shfl_xor(acc[k].x, 32);
        acc[k].y += __shfl_xor(acc[k].y, 32);
        acc[k].z += __shfl_xor(acc[k].z, 32);
        acc[k].w += __shfl_xor(acc[k].w, 32);
    }

    if (nl == 0) {
#pragma unroll
        for (int k = 0; k < K_FILT; k++)
            *(float4*)&pO[((size_t)(nc * K_FILT + k) * BATCH + b) * FEAT + f0] = acc[k];
    }
}

// ============================================================================
// FALLBACK PATH (round-1 atomics) — used only if ws is too small
// ============================================================================
__global__ void zero_ws_kernel(float* __restrict__ p, int n) {
    int i = blockIdx.x * blockDim.x + threadIdx.x;
    if (i < n) p[i] = 0.0f;
}

__global__ __launch_bounds__(256) void wl_atomic_kernel(const float* __restrict__ W,
                                                        const float* __restrict__ L,
                                                        float* __restrict__ wL) {
    const int ntile = blockIdx.x & 7;
    const int mc    = blockIdx.x >> 3;
    const int n0    = ntile * 1024;
    const int m0    = mc * 128;
    __shared__ float Ws[K_FILT][128];
    for (int idx = threadIdx.x; idx < K_FILT * 128; idx += 256) {
        int k = idx >> 7, j = idx & 127;
        Ws[k][j] = W[k * N_SIMP + m0 + j];
    }
    __syncthreads();
    const int n = n0 + threadIdx.x * 4;
    float4 acc[K_FILT];
#pragma unroll
    for (int k = 0; k < K_FILT; k++) acc[k] = make_float4(0.f, 0.f, 0.f, 0.f);
    const float* Lp = L + (size_t)m0 * N_SIMP + n;
    for (int j = 0; j < 128; j++) {
        float4 lv = *(const float4*)Lp;
        Lp += N_SIMP;
#pragma unroll
        for (int k = 0; k < K_FILT; k++) {
            float w = Ws[k][j];
            acc[k].x += w * lv.x; acc[k].y += w * lv.y; acc[k].z += w * lv.z; acc[k].w += w * lv.w;
        }
    }
#pragma unroll
    for (int k = 0; k < K_FILT; k++) {
        float* dst = &wL[k * N_SIMP + n];
        atomicAdd(dst + 0, acc[k].x); atomicAdd(dst + 1, acc[k].y);
        atomicAdd(dst + 2, acc[k].z); atomicAdd(dst + 3, acc[k].w);
    }
}

__global__ __launch_bounds__(64) void conv_atomic_kernel(const float* __restrict__ wL,
                                                         const float* __restrict__ x,
                                                         float* __restrict__ out_acc) {
    const int nc   = blockIdx.x & 63;
    const int b    = blockIdx.x >> 6;
    const int n0   = nc * 128;
    const int lane = threadIdx.x;
    const int f0   = (lane & 31) * 4;
    const int nl   = lane >> 5;
    __shared__ float wls[K_FILT][128];
    for (int idx = lane; idx < K_FILT * 128; idx += 64) {
        int k = idx >> 7, j = idx & 127;
        wls[k][j] = wL[k * N_SIMP + n0 + j];
    }
    __syncthreads();
    float4 acc[K_FILT];
#pragma unroll
    for (int k = 0; k < K_FILT; k++) acc[k] = make_float4(0.f, 0.f, 0.f, 0.f);
    const float* xp = x + (size_t)b * N_SIMP * FEAT + (size_t)(n0 + nl) * FEAT + f0;
    for (int jj = 0; jj < 64; jj++) {
        int j = jj * 2 + nl;
        float4 xv = *(const float4*)xp;
        xp += 2 * FEAT;
#pragma unroll
        for (int k = 0; k < K_FILT; k++) {
            float w = wls[k][j];
            acc[k].x += w * xv.x; acc[k].y += w * xv.y; acc[k].z += w * xv.z; acc[k].w += w * xv.w;
        }
    }
#pragma unroll
    for (int k = 0; k < K_FILT; k++) {
        acc[k].x += __shfl_xor(acc[k].x, 32);
        acc[k].y += __shfl_xor(acc[k].y, 32);
        acc[k].z += __shfl_xor(acc[k].z, 32);
        acc[k].w += __shfl_xor(acc[k].w, 32);
    }
    if (nl == 0) {
#pragma unroll
        for (int k = 0; k < K_FILT; k++) {
            float* dst = &out_acc[((size_t)k * BATCH + b) * FEAT + f0];
            atomicAdd(dst + 0, acc[k].x); atomicAdd(dst + 1, acc[k].y);
            atomicAdd(dst + 2, acc[k].z); atomicAdd(dst + 3, acc[k].w);
        }
    }
}

__global__ void tanh_kernel(const float* __restrict__ acc, float* __restrict__ out) {
    int i = blockIdx.x * blockDim.x + threadIdx.x;
    if (i < K_FILT * BATCH * FEAT) out[i] = tanhf(acc[i]);
}

// ============================================================================
extern "C" void kernel_launch(void* const* d_in, const int* in_sizes, int n_in,
                              void* d_out, int out_size, void* d_ws, size_t ws_size,
                              hipStream_t stream) {
    const float* x = (const float*)d_in[0];  // [64, 8192, 128]
    const float* L = (const float*)d_in[1];  // [8192, 8192]
    const float* W = (const float*)d_in[2];  // [8, 8192]
    float* out = (float*)d_out;              // [8, 64, 128]

    const size_t partial_elems = (size_t)MCHUNK * K_FILT * N_SIMP;  // == NCHUNK*K*B*F = 4M floats
    const size_t need = (partial_elems + K_FILT * N_SIMP) * sizeof(float);  // 16 MB + 256 KB

    if (ws_size >= need) {
        float* partials = (float*)d_ws;                 // 16 MB (pL, then reused as pO)
        float* wL       = partials + partial_elems;     // 256 KB

        wl_partial_kernel<<<8 * MCHUNK, 256, 0, stream>>>(W, L, partials);
        reduce64_kernel<false><<<256, 256, 0, stream>>>(partials, wL);
        conv_partial_kernel<<<BATCH * NCHUNK, 64, 0, stream>>>(wL, x, partials);
        reduce64_kernel<true><<<256, 256, 0, stream>>>(partials, out);
    } else {
        float* wL      = (float*)d_ws;
        float* out_acc = wL + (size_t)K_FILT * N_SIMP;
        const int n_zero = K_FILT * N_SIMP + K_FILT * BATCH * FEAT;
        zero_ws_kernel<<<(n_zero + 255) / 256, 256, 0, stream>>>(wL, n_zero);
        wl_atomic_kernel<<<512, 256, 0, stream>>>(W, L, wL);
        conv_atomic_kernel<<<BATCH * 64, 64, 0, stream>>>(wL, x, out_acc);
        tanh_kernel<<<(K_FILT * BATCH * FEAT + 255) / 256, 256, 0, stream>>>(out_acc, out);
    }
}